// Round 1
// 291.796 us; speedup vs baseline: 1.0156x; 1.0156x over previous
//
#include <hip/hip_runtime.h>

// ConvRecLayer: dynamic conv (H=16, K=15, causal) + LayerNorm + FFN(relu) + residual
// T=1024 B=8 C=1024 F=4096. Inputs/outputs fp32 (per reference); internal compute bf16 MFMA.

#define T_DIM 1024
#define B_DIM 8
#define C_DIM 1024
#define F_DIM 4096
#define H_DIM 16
#define K_TAP 15
#define TB (T_DIM * B_DIM)   // 8192 rows

typedef __attribute__((ext_vector_type(8))) short short8;
typedef __attribute__((ext_vector_type(4))) float f32x4;

__device__ __forceinline__ float bf2f(unsigned short u) {
    union { unsigned int i; float f; } v; v.i = ((unsigned int)u) << 16; return v.f;
}
__device__ __forceinline__ unsigned short f2bf(float f) {
    union { float f; unsigned int i; } v; v.f = f;
    unsigned int r = v.i + 0x7fffu + ((v.i >> 16) & 1u);  // RNE
    return (unsigned short)(r >> 16);
}

// async global->LDS DMA, 16B per lane: lane i reads gptr(lane) -> ldsbase + i*16
__device__ __forceinline__ void async_copy16(const void* gptr, void* lptr) {
    __builtin_amdgcn_global_load_lds(
        (const __attribute__((address_space(1))) void*)gptr,
        (__attribute__((address_space(3))) void*)lptr, 16, 0, 0);
}

// ---------------------------------------------------------------------------
// prep: fused fp32->bf16 convert of x + three fp32->bf16 transposes.
// ---------------------------------------------------------------------------
__global__ __launch_bounds__(256)
void prep(const float* __restrict__ x, unsigned short* __restrict__ xb,
          const float* __restrict__ fc1_w, unsigned short* __restrict__ fc1T,
          const float* __restrict__ fc2_w, unsigned short* __restrict__ fc2T,
          const float* __restrict__ w_lin, unsigned short* __restrict__ wlinT) {
    const int bid = blockIdx.x;
    const int tid = threadIdx.x;
    if (bid < 8192) {
        int i = (bid * 256 + tid) * 4;
        float4 v = *(const float4*)(x + i);
        uint2 o;
        o.x = (unsigned int)f2bf(v.x) | ((unsigned int)f2bf(v.y) << 16);
        o.y = (unsigned int)f2bf(v.z) | ((unsigned int)f2bf(v.w) << 16);
        *(uint2*)(xb + i) = o;
        return;
    }
    // transpose path
    const float* in; unsigned short* out; int R, Cin, c0, r0;
    if (bid < 12288) {
        int idx = bid - 8192;                 // grid (128, 32)
        in = fc1_w; out = fc1T; R = C_DIM; Cin = F_DIM;
        c0 = (idx & 127) * 32; r0 = (idx >> 7) * 32;
    } else if (bid < 16384) {
        int idx = bid - 12288;                // grid (32, 128)
        in = fc2_w; out = fc2T; R = F_DIM; Cin = C_DIM;
        c0 = (idx & 31) * 32; r0 = (idx >> 5) * 32;
    } else {
        int idx = bid - 16384;                // grid (8, 32)
        in = w_lin; out = wlinT; R = C_DIM; Cin = 240;
        c0 = (idx & 7) * 32; r0 = (idx >> 3) * 32;
    }
    __shared__ unsigned short tile[32][33];
    const int xx = tid & 31, yy = tid >> 5;   // 32 x 8
#pragma unroll
    for (int j = 0; j < 4; j++) {
        int r = r0 + yy + j * 8, c = c0 + xx;
        unsigned short v = 0;
        if (c < Cin) v = f2bf(in[(size_t)r * Cin + c]);
        tile[yy + j * 8][xx] = v;
    }
    __syncthreads();
#pragma unroll
    for (int j = 0; j < 4; j++) {
        out[(size_t)(c0 + yy + j * 8) * R + (r0 + xx)] = tile[xx][yy + j * 8];
    }
}

// ---------------------------------------------------------------------------
// gemm_bt: 128x128-tile kernel (m97 structure, ~842 TF). Retained for the
// wscore GEMM (N=256) and fc2 (N=1024 -> 512 blocks; 256^2 tile would only
// make 128 blocks = half the CUs idle).
// MODE 2: fp32 out = acc + bias[n] + resid[m][n]   (resid bf16)
// MODE 3: fp32 out = acc (partial per z)
// ---------------------------------------------------------------------------
template <int MODE, int SWAP>
__global__ __launch_bounds__(256)
void gemm_bt(const unsigned short* __restrict__ A,
             const unsigned short* __restrict__ Bt,
             void* __restrict__ Cout_v,
             int M, int N, int K, int kz,
             const float* __restrict__ bias,
             const unsigned short* __restrict__ resid) {
    __shared__ __align__(16) unsigned short As[2][128 * 64];
    __shared__ __align__(16) unsigned short Bs[2][128 * 64];

    const int tid = threadIdx.x;
    const int m0 = (SWAP ? blockIdx.x : blockIdx.y) * 128;
    const int n0 = (SWAP ? blockIdx.y : blockIdx.x) * 128;
    const int kbase = blockIdx.z * kz;
    const int wave = tid >> 6, lane = tid & 63;
    const int quad = lane >> 4, l16 = lane & 15;
    const int wm = (wave >> 1) * 64;  // wave row offset in tile
    const int wn = (wave & 1) * 64;   // wave col offset in tile

    f32x4 acc[4][4];
#pragma unroll
    for (int i = 0; i < 4; i++)
#pragma unroll
        for (int j = 0; j < 4; j++) acc[i][j] = (f32x4){0.f, 0.f, 0.f, 0.f};

    const int rsub = lane >> 3;                   // 0..7
    const int gch = (lane & 7) ^ rsub;            // swizzled global chunk
    const unsigned short* gA = A + (size_t)(m0 + wave * 32 + rsub) * K + kbase + gch * 8;
    const unsigned short* gB = Bt + (size_t)(n0 + wave * 32 + rsub) * K + kbase + gch * 8;
    unsigned short* lA[2] = {&As[0][wave * 32 * 64], &As[1][wave * 32 * 64]};
    unsigned short* lB[2] = {&Bs[0][wave * 32 * 64], &Bs[1][wave * 32 * 64]};

    // prologue: stage tile 0 into buffer 0
#pragma unroll
    for (int j = 0; j < 4; j++) {
        async_copy16(gA + (size_t)j * 8 * K, lA[0] + j * 8 * 64);
        async_copy16(gB + (size_t)j * 8 * K, lB[0] + j * 8 * 64);
    }

    const int swz = l16 & 7;                      // fragment-read swizzle
    int buf = 0;
    for (int k0 = 0; k0 < kz; k0 += 64) {
        __syncthreads();   // drains own-wave DMA (tile k) + all waves' reads of buf^1

        const int nk = k0 + 64;
        if (nk < kz) {     // prefetch tile k+1 into the other buffer
            const int nb = buf ^ 1;
#pragma unroll
            for (int j = 0; j < 4; j++) {
                async_copy16(gA + nk + (size_t)j * 8 * K, lA[nb] + j * 8 * 64);
                async_copy16(gB + nk + (size_t)j * 8 * K, lB[nb] + j * 8 * 64);
            }
        }

        short8 af[2][4], bfr[2][4];
#pragma unroll
        for (int kk = 0; kk < 2; kk++) {
            const int c = kk * 4 + quad;          // global chunk for this kk
#pragma unroll
            for (int i = 0; i < 4; i++) {
                af[kk][i]  = *(const short8*)(&As[buf][(wm + i * 16 + l16) * 64 + (c ^ swz) * 8]);
                bfr[kk][i] = *(const short8*)(&Bs[buf][(wn + i * 16 + l16) * 64 + (c ^ swz) * 8]);
            }
        }
#pragma unroll
        for (int kk = 0; kk < 2; kk++)
#pragma unroll
            for (int mi = 0; mi < 4; mi++)
#pragma unroll
                for (int nj = 0; nj < 4; nj++)
                    acc[mi][nj] = __builtin_amdgcn_mfma_f32_16x16x32_bf16(
                        af[kk][mi], bfr[kk][nj], acc[mi][nj], 0, 0, 0);
        buf ^= 1;
    }

    // epilogue: lane holds D[row=quad*4+i][col=l16] per 16x16 tile
    const int crow0 = m0 + wm + quad * 4;
    const int ccol0 = n0 + wn + l16;
    if (MODE == 3) {
        float* Cf = (float*)Cout_v + (size_t)blockIdx.z * M * N;
#pragma unroll
        for (int mi = 0; mi < 4; mi++)
#pragma unroll
            for (int i = 0; i < 4; i++) {
                int rr = crow0 + mi * 16 + i;
#pragma unroll
                for (int nj = 0; nj < 4; nj++)
                    Cf[(size_t)rr * N + ccol0 + nj * 16] = acc[mi][nj][i];
            }
    } else if (MODE == 1) {
        unsigned short* Cb = (unsigned short*)Cout_v;
        float bv[4];
#pragma unroll
        for (int nj = 0; nj < 4; nj++) bv[nj] = bias[ccol0 + nj * 16];
#pragma unroll
        for (int mi = 0; mi < 4; mi++)
#pragma unroll
            for (int i = 0; i < 4; i++) {
                int rr = crow0 + mi * 16 + i;
#pragma unroll
                for (int nj = 0; nj < 4; nj++) {
                    float v = fmaxf(acc[mi][nj][i] + bv[nj], 0.f);
                    Cb[(size_t)rr * N + ccol0 + nj * 16] = f2bf(v);
                }
            }
    } else {  // MODE 2
        float* Cf = (float*)Cout_v;
        float bv[4];
#pragma unroll
        for (int nj = 0; nj < 4; nj++) bv[nj] = bias[ccol0 + nj * 16];
#pragma unroll
        for (int mi = 0; mi < 4; mi++)
#pragma unroll
            for (int i = 0; i < 4; i++) {
                int rr = crow0 + mi * 16 + i;
#pragma unroll
                for (int nj = 0; nj < 4; nj++) {
                    float v = acc[mi][nj][i] + bv[nj]
                            + bf2f(resid[(size_t)rr * N + ccol0 + nj * 16]);
                    Cf[(size_t)rr * N + ccol0 + nj * 16] = v;
                }
            }
    }
}

// ---------------------------------------------------------------------------
// gemm256_relu: 256x256-tile, BK=64, 512 threads (8 waves, 2Mx4N), 8-phase
// schedule with counted vmcnt (T3+T4) + setprio MFMA clusters (T5).
// C[M x N] = relu(A[M x K] @ Bt[N x K]^T + bias), bf16 out.  (fc1 only)
//
// Wave (wr=wave>>2, wc=wave&3) owns rows {wr*64..+63} in BOTH A-halves and
// cols {wc*32..+31} in BOTH B-halves, so phase (qm,qn) consumes exactly
// LDS halves Ah[qm]/Bh[qn] for ALL waves:
//   P0=(0,0) read af0(8)+bfr(4) | P1=(1,0) read af1(8), bfr reused
//   P2=(1,1) read bfr(4), af1 reused | P3=(0,1) no reads (af0+bfr reused)
// Staging 1 half-tile/phase (2 x global_load_lds, 16B/lane):
//   P0->Ah0(t+1)  P1->Bh1(t+1)  P2->Bh0(t+2)  P3->Ah1(t+2)
// Region-death: each half's ds_reads drain at that phase's lgkmcnt(0), so
// every stage target is dead before its issue point (barrier-separated).
// ONE s_waitcnt vmcnt(4) per K-tile (at P3, before the boundary barrier)
// covers all of tile t+1's halves while leaving 2 half-tiles (4 loads) in
// flight -- never vmcnt(0) in the loop.
// LDS 128 KiB (2 buf x 2 half x 128x64 x A,B), 1 block/CU.
// Same chunk^(row&7) swizzle as gemm_bt (verified conflict-free).
// Requires M%256==0, N%256==0, K%64==0, K>=128.
// ---------------------------------------------------------------------------
__global__ __launch_bounds__(512, 2)
void gemm256_relu(const unsigned short* __restrict__ A,
                  const unsigned short* __restrict__ Bt,
                  unsigned short* __restrict__ C,
                  const int M, const int N, const int K,
                  const float* __restrict__ bias) {
    __shared__ __align__(16) unsigned short As[2][2][128 * 64];
    __shared__ __align__(16) unsigned short Bs[2][2][128 * 64];

    const int tid = threadIdx.x;
    const int m0 = blockIdx.y * 256;
    const int n0 = blockIdx.x * 256;
    const int wave = tid >> 6, lane = tid & 63;
    const int quad = lane >> 4, l16 = lane & 15;
    const int wr = wave >> 2;        // 0..1
    const int wc = wave & 3;         // 0..3
    const int swz = l16 & 7;

    const int rsub = tid >> 3;                    // 0..63
    const int gch = (tid & 7) ^ (rsub & 7);       // swizzled global chunk
    const int nt = K >> 6;

// stage one 128x64 half-tile: rows [row0, row0+128) of G, k-cols [kt*64, +64)
// LDS dest is lane-linear (DMA requirement); swizzle applied on global side.
#define STAGE(G, row0, kt, L) do {                                             \
    const unsigned short* _g = (G) + (size_t)((row0) + rsub) * K               \
                             + (kt) * 64 + gch * 8;                            \
    unsigned short* _l = (L) + tid * 8;                                        \
    async_copy16(_g, _l);                                                      \
    async_copy16(_g + (size_t)64 * K, _l + 4096);                              \
} while (0)

    f32x4 acc[8][4];
#pragma unroll
    for (int i = 0; i < 8; i++)
#pragma unroll
        for (int j = 0; j < 4; j++) acc[i][j] = (f32x4){0.f, 0.f, 0.f, 0.f};

    // prologue: tile0 all 4 halves, then tile1's Bh0+Ah1 (pattern offset)
    STAGE(A,  m0,       0, &As[0][0][0]);
    STAGE(Bt, n0,       0, &Bs[0][0][0]);
    STAGE(A,  m0 + 128, 0, &As[0][1][0]);
    STAGE(Bt, n0 + 128, 0, &Bs[0][1][0]);
    STAGE(Bt, n0,       1, &Bs[1][0][0]);
    STAGE(A,  m0 + 128, 1, &As[1][1][0]);
    asm volatile("s_waitcnt vmcnt(4)" ::: "memory");   // tile0 landed; tile1 halves in flight
    __builtin_amdgcn_s_barrier();

    int buf = 0;
    for (int t = 0; t < nt; ++t) {
        const int nb = buf ^ 1;
        const int k1 = (t + 1 < nt) ? t + 1 : nt - 1;   // clamped (tail stages harmless)
        const int k2 = (t + 2 < nt) ? t + 2 : nt - 1;
        short8 af0[2][4], af1[2][4], bfr[2][2];

        // ---- P0: (qm=0, qn=0) ------------------------------------------
#pragma unroll
        for (int kk = 0; kk < 2; kk++) {
            const int sl = ((kk * 4 + quad) ^ swz) * 8;
#pragma unroll
            for (int mi = 0; mi < 4; mi++)
                af0[kk][mi] = *(const short8*)&As[buf][0][(wr * 64 + mi * 16 + l16) * 64 + sl];
#pragma unroll
            for (int nj = 0; nj < 2; nj++)
                bfr[kk][nj] = *(const short8*)&Bs[buf][0][(wc * 32 + nj * 16 + l16) * 64 + sl];
        }
        STAGE(A, m0, k1, &As[nb][0][0]);
        __builtin_amdgcn_s_barrier();
        asm volatile("s_waitcnt lgkmcnt(0)" ::: "memory");
        __builtin_amdgcn_sched_barrier(0);
        __builtin_amdgcn_s_setprio(1);
#pragma unroll
        for (int kk = 0; kk < 2; kk++)
#pragma unroll
            for (int mi = 0; mi < 4; mi++)
#pragma unroll
                for (int nj = 0; nj < 2; nj++)
                    acc[mi][nj] = __builtin_amdgcn_mfma_f32_16x16x32_bf16(
                        af0[kk][mi], bfr[kk][nj], acc[mi][nj], 0, 0, 0);
        __builtin_amdgcn_s_setprio(0);
        __builtin_amdgcn_s_barrier();

        // ---- P1: (qm=1, qn=0), bfr reused ------------------------------
#pragma unroll
        for (int kk = 0; kk < 2; kk++) {
            const int sl = ((kk * 4 + quad) ^ swz) * 8;
#pragma unroll
            for (int mi = 0; mi < 4; mi++)
                af1[kk][mi] = *(const short8*)&As[buf][1][(wr * 64 + mi * 16 + l16) * 64 + sl];
        }
        STAGE(Bt, n0 + 128, k1, &Bs[nb][1][0]);
        __builtin_amdgcn_s_barrier();
        asm volatile("s_waitcnt lgkmcnt(0)" ::: "memory");
        __builtin_amdgcn_sched_barrier(0);
        __builtin_amdgcn_s_setprio(1);
#pragma unroll
        for (int kk = 0; kk < 2; kk++)
#pragma unroll
            for (int mi = 0; mi < 4; mi++)
#pragma unroll
                for (int nj = 0; nj < 2; nj++)
                    acc[4 + mi][nj] = __builtin_amdgcn_mfma_f32_16x16x32_bf16(
                        af1[kk][mi], bfr[kk][nj], acc[4 + mi][nj], 0, 0, 0);
        __builtin_amdgcn_s_setprio(0);
        __builtin_amdgcn_s_barrier();

        // ---- P2: (qm=1, qn=1), af1 reused ------------------------------
#pragma unroll
        for (int kk = 0; kk < 2; kk++) {
            const int sl = ((kk * 4 + quad) ^ swz) * 8;
#pragma unroll
            for (int nj = 0; nj < 2; nj++)
                bfr[kk][nj] = *(const short8*)&Bs[buf][1][(wc * 32 + nj * 16 + l16) * 64 + sl];
        }
        STAGE(Bt, n0, k2, &Bs[buf][0][0]);
        __builtin_amdgcn_s_barrier();
        asm volatile("s_waitcnt lgkmcnt(0)" ::: "memory");
        __builtin_amdgcn_sched_barrier(0);
        __builtin_amdgcn_s_setprio(1);
#pragma unroll
        for (int kk = 0; kk < 2; kk++)
#pragma unroll
            for (int mi = 0; mi < 4; mi++)
#pragma unroll
                for (int nj = 0; nj < 2; nj++)
                    acc[4 + mi][2 + nj] = __builtin_amdgcn_mfma_f32_16x16x32_bf16(
                        af1[kk][mi], bfr[kk][nj], acc[4 + mi][2 + nj], 0, 0, 0);
        __builtin_amdgcn_s_setprio(0);
        __builtin_amdgcn_s_barrier();

        // ---- P3: (qm=0, qn=1), af0+bfr reused; tile-boundary wait -------
        STAGE(A, m0 + 128, k2, &As[buf][1][0]);
        __builtin_amdgcn_s_barrier();
        asm volatile("s_waitcnt lgkmcnt(0)" ::: "memory");
        __builtin_amdgcn_sched_barrier(0);
        __builtin_amdgcn_s_setprio(1);
#pragma unroll
        for (int kk = 0; kk < 2; kk++)
#pragma unroll
            for (int mi = 0; mi < 4; mi++)
#pragma unroll
                for (int nj = 0; nj < 2; nj++)
                    acc[mi][2 + nj] = __builtin_amdgcn_mfma_f32_16x16x32_bf16(
                        af0[kk][mi], bfr[kk][nj], acc[mi][2 + nj], 0, 0, 0);
        __builtin_amdgcn_s_setprio(0);
        asm volatile("s_waitcnt vmcnt(4)" ::: "memory");  // tile t+1 fully landed
        __builtin_amdgcn_s_barrier();

        buf = nb;
    }
    asm volatile("s_waitcnt vmcnt(0)" ::: "memory");  // drain tail DMAs
#undef STAGE

    // epilogue: frag (fm=qm*4+mi, fn=qn*2+nj); lane holds rows quad*4+i, col l16
    const int crow = m0 + wr * 64 + quad * 4;
    const int ccol = n0 + wc * 32 + l16;
    float bv[4];
#pragma unroll
    for (int fn = 0; fn < 4; fn++)
        bv[fn] = bias[ccol + (fn >> 1) * 128 + (fn & 1) * 16];
#pragma unroll
    for (int fm = 0; fm < 8; fm++) {
        const int rr0 = crow + (fm >> 2) * 128 + (fm & 3) * 16;
#pragma unroll
        for (int i = 0; i < 4; i++) {
            const int rr = rr0 + i;
#pragma unroll
            for (int fn = 0; fn < 4; fn++) {
                const int cc = ccol + (fn >> 1) * 128 + (fn & 1) * 16;
                float v = fmaxf(acc[fm][fn][i] + bv[fn], 0.f);
                C[(size_t)rr * N + cc] = f2bf(v);
            }
        }
    }
}

// ---------------------------------------------------------------------------
// conv_ln16s: tap-softmax + causal dynamic conv + LayerNorm (unchanged).
// ---------------------------------------------------------------------------
#define XSP 1032   // padded LDS row stride (bf16 elems)
#define WS_STRIDE ((size_t)TB * 256)
__global__ __launch_bounds__(256)
void conv_ln16s(const unsigned short* __restrict__ xb,
                const float* __restrict__ wscore,
                const float* __restrict__ b_lin,
                const float* __restrict__ ln_g,
                const float* __restrict__ ln_b,
                unsigned short* __restrict__ y) {
    __shared__ __align__(16) unsigned short xs[30 * XSP];   // 60.5 KiB
    __shared__ float wls[16 * 240];                         // 15 KiB
    const int blk = blockIdx.x;          // 0..511
    const int b = blk & 7;
    const int t0 = (blk >> 3) * 16;
    const int tid = threadIdx.x;

    // phase 1 (issue first: independent of x staging): per-(row, head) softmax
    {
        const int row = tid >> 4, hh = tid & 15;
        const size_t grow = (size_t)(t0 + row) * B_DIM + b;
        const float* p = wscore + grow * 256 + hh * K_TAP;
        float v[K_TAP], mx = -1e30f;
#pragma unroll
        for (int k = 0; k < K_TAP; k++) {
            v[k] = p[k] + p[k + WS_STRIDE] + b_lin[hh * K_TAP + k];
            mx = fmaxf(mx, v[k]);
        }
        float s = 0.f;
#pragma unroll
        for (int k = 0; k < K_TAP; k++) { v[k] = __expf(v[k] - mx); s += v[k]; }
        float inv = 1.0f / s;
#pragma unroll
        for (int k = 0; k < K_TAP; k++) wls[row * 240 + hh * K_TAP + k] = v[k] * inv;
    }

    // phase 0: stage 30 x-rows, 8B per thread per row
#pragma unroll
    for (int j = 0; j < 30; j++) {
        int t = t0 + j - 14;
        uint2 val = make_uint2(0u, 0u);
        if (t >= 0)
            val = *(const uint2*)(xb + ((size_t)t * B_DIM + b) * C_DIM + tid * 4);
        *(uint2*)(&xs[j * XSP + tid * 4]) = val;
    }
    __syncthreads();

    // phase 2: conv + LN. wave handles rows wave, wave+4, wave+8, wave+12.
    const int wave = tid >> 6, lane = tid & 63;
    const int ch0 = lane * 16;
    const int h = lane >> 2;             // head index, constant over lane's 16 ch
    for (int rj = wave; rj < 16; rj += 4) {
        float o[16];
#pragma unroll
        for (int i = 0; i < 16; i++) o[i] = 0.f;
#pragma unroll
        for (int k = 0; k < K_TAP; k++) {
            float w = wls[rj * 240 + h * K_TAP + k];
            const unsigned short* xr = &xs[(rj + k) * XSP + ch0];
            uint4 p0 = *(const uint4*)(xr);
            uint4 p1 = *(const uint4*)(xr + 8);
            unsigned int uu[8] = {p0.x, p0.y, p0.z, p0.w, p1.x, p1.y, p1.z, p1.w};
#pragma unroll
            for (int q = 0; q < 8; q++) {
                o[2 * q]     += w * bf2f((unsigned short)(uu[q] & 0xffff));
                o[2 * q + 1] += w * bf2f((unsigned short)(uu[q] >> 16));
            }
        }
        float s = 0.f, s2 = 0.f;
#pragma unroll
        for (int i = 0; i < 16; i++) { s += o[i]; s2 += o[i] * o[i]; }
#pragma unroll
        for (int off = 32; off > 0; off >>= 1) {
            s  += __shfl_xor(s, off, 64);
            s2 += __shfl_xor(s2, off, 64);
        }
        float mu = s * (1.0f / C_DIM);
        float var = s2 * (1.0f / C_DIM) - mu * mu;
        float rs = rsqrtf(var + 1e-5f);

        unsigned short o16[16];
#pragma unroll
        for (int i = 0; i < 16; i++)
            o16[i] = f2bf((o[i] - mu) * rs * ln_g[ch0 + i] + ln_b[ch0 + i]);
        uint4 w0, w1;
        w0.x = (unsigned int)o16[0]  | ((unsigned int)o16[1]  << 16);
        w0.y = (unsigned int)o16[2]  | ((unsigned int)o16[3]  << 16);
        w0.z = (unsigned int)o16[4]  | ((unsigned int)o16[5]  << 16);
        w0.w = (unsigned int)o16[6]  | ((unsigned int)o16[7]  << 16);
        w1.x = (unsigned int)o16[8]  | ((unsigned int)o16[9]  << 16);
        w1.y = (unsigned int)o16[10] | ((unsigned int)o16[11] << 16);
        w1.z = (unsigned int)o16[12] | ((unsigned int)o16[13] << 16);
        w1.w = (unsigned int)o16[14] | ((unsigned int)o16[15] << 16);
        unsigned short* yr = y + ((size_t)(t0 + rj) * B_DIM + b) * C_DIM + ch0;
        *(uint4*)(yr) = w0;
        *(uint4*)(yr + 8) = w1;
    }
}

// ---------------------------------------------------------------------------
extern "C" void kernel_launch(void* const* d_in, const int* in_sizes, int n_in,
                              void* d_out, int out_size, void* d_ws, size_t ws_size,
                              hipStream_t stream) {
    const float* x     = (const float*)d_in[0];
    const float* w_lin = (const float*)d_in[1];
    const float* b_lin = (const float*)d_in[2];
    const float* ln_g  = (const float*)d_in[3];
    const float* ln_b  = (const float*)d_in[4];
    const float* fc1_w = (const float*)d_in[5];
    const float* fc1_b = (const float*)d_in[6];
    const float* fc2_w = (const float*)d_in[7];
    const float* fc2_b = (const float*)d_in[8];
    float* out = (float*)d_out;

    // workspace layout (bytes); total ~112.5 MiB
    char* ws = (char*)d_ws;
    unsigned short* xb    = (unsigned short*)(ws);                      // TB x C   16 MiB
    unsigned short* fc1T  = (unsigned short*)(ws + 16777216);           // F x C     8 MiB
    unsigned short* fc2T  = (unsigned short*)(ws + 25165824);           // C x F     8 MiB
    unsigned short* wlinT = (unsigned short*)(ws + 33554432);           // 256 x C   0.5 MiB
    unsigned short* y     = (unsigned short*)(ws + 34078720);           // TB x C   16 MiB
    unsigned short* h     = (unsigned short*)(ws + 50855936);           // TB x F   64 MiB
    // wscore (2 split-K partials) overlaps h's region (dead before fc1)
    float* wscore = (float*)(ws + 50855936);                            // 2 x TB x 256 fp32 (16 MiB)

    // fused convert + transposes (1 launch)
    prep<<<16640, 256, 0, stream>>>(x, xb, fc1_w, fc1T, fc2_w, fc2T, w_lin, wlinT);

    // conv-weight logits: wscore[z] = xb @ wlinT K-slice (split-K=2, 256 blocks)
    gemm_bt<3, 0><<<dim3(256 / 128, TB / 128, 2), 256, 0, stream>>>(
        xb, wlinT, (void*)wscore, TB, 256, C_DIM, C_DIM / 2, nullptr, nullptr);

    // fused softmax + dynamic conv + LayerNorm -> y (bf16), 16 rows per block
    conv_ln16s<<<TB / 16, 256, 0, stream>>>(xb, wscore, b_lin, ln_g, ln_b, y);

    // h = relu(y @ fc1_w + fc1_b)  (bf16) -- 256^2 8-phase kernel, 512 blocks
    gemm256_relu<<<dim3(F_DIM / 256, TB / 256), 512, 0, stream>>>(
        y, fc1T, h, TB, F_DIM, C_DIM, fc1_b);

    // out = h @ fc2_w + fc2_b + y  (fp32); m-tile on x for same-XCD h reuse
    gemm_bt<2, 1><<<dim3(TB / 128, C_DIM / 128, 1), 256, 0, stream>>>(
        h, fc2T, (void*)out, TB, C_DIM, F_DIM, F_DIM, fc2_b, y);
}